// Round 5
// baseline (348.016 us; speedup 1.0000x reference)
//
#include <hip/hip_runtime.h>
#include <hip/hip_bf16.h>

// Deter GRU cell on MI355X. bf16 MFMA GEMMs, global_load_lds staging into a
// 3-buffer LDS pipeline (2 tiles in flight, counted vmcnt - never drained to 0
// in the main loop), split-K bf16 partials summed in fused RMSNorm consumers.
// Weights transposed+converted to bf16 [N][K] once per call.

typedef unsigned short u16;
typedef unsigned int u32;
typedef __attribute__((ext_vector_type(8))) __bf16 bf16x8;
typedef __attribute__((ext_vector_type(4))) float f32x4;

#define AS3 __attribute__((address_space(3)))
#define AS1 __attribute__((address_space(1)))

__device__ __forceinline__ u16 f2bf(float f) {
    union { float f; u32 u; } a; a.f = f;
    u32 r = a.u + 0x7FFFu + ((a.u >> 16) & 1u);
    return (u16)(r >> 16);
}
__device__ __forceinline__ float bf2f(u16 h) {
    union { u32 u; float f; } c; c.u = ((u32)h) << 16; return c.f;
}
__device__ __forceinline__ u32 pk2(float a, float b) {
    return (u32)f2bf(a) | ((u32)f2bf(b) << 16);
}
__device__ __forceinline__ void gload16(const u16* g, char* lds) {
    __builtin_amdgcn_global_load_lds((const AS1 u32*)g, (AS3 u32*)lds, 16, 0, 0);
}

// ---- core 128x128 GEMM tile, BK=32, 4 waves --------------------------------
// 3 LDS buffers per operand (8 KB each). Pipeline: stage t,t+1,t+2 ahead;
// per iter: vmcnt(8) [stage(t) landed, 2 ahead in flight] -> barrier ->
// ds_read frags -> MFMA -> barrier -> stage(t+3) into buf(t%3).
// 16B-slot swizzle: LDS[r][s] holds global slot s ^ ((r>>1)&3).
__device__ __forceinline__ void gemm_core128(
    const u16* __restrict__ A1, int lda1, int acol, int K1,
    const u16* __restrict__ A2, int lda2,
    const u16* __restrict__ Wtg, int ldw, int n0,
    const float* __restrict__ bias, int addBias,
    u16* __restrict__ Cb, int ldc, int col0,
    int m0, int kbeg, int nk, u16* As, u16* Bs)
{
    const int t = threadIdx.x;
    const int lane = t & 63;
    const int wv = t >> 6;
    const int wr = (wv >> 1) << 6;
    const int wc = (wv & 1) << 6;
    const int lr = lane & 15;
    const int hi = lane >> 4;

    const int srow  = lane >> 2;
    const int scol8 = ((lane & 3) ^ ((lane >> 3) & 3)) * 8;
    const int fs = (hi ^ ((lr >> 1) & 3)) * 8;

    f32x4 acc[4][4];
    #pragma unroll
    for (int i = 0; i < 4; ++i)
        #pragma unroll
        for (int j = 0; j < 4; ++j)
            acc[i][j] = (f32x4){0.f, 0.f, 0.f, 0.f};

    auto stage = [&](int k0c, int bufbyte) {
        const u16* asrc; int alda; int ac;
        if (k0c < K1) { asrc = A1; alda = lda1; ac = acol + k0c; }
        else          { asrc = A2; alda = lda2; ac = k0c - K1; }
        const int lo0 = __builtin_amdgcn_readfirstlane(bufbyte + wv * 1024);
        const int lo1 = __builtin_amdgcn_readfirstlane(bufbyte + 4096 + wv * 1024);
        gload16(asrc + (size_t)(m0 + wv * 16 + srow) * alda + ac + scol8, (char*)As + lo0);
        gload16(asrc + (size_t)(m0 + 64 + wv * 16 + srow) * alda + ac + scol8, (char*)As + lo1);
        gload16(Wtg + (size_t)(n0 + wv * 16 + srow) * ldw + k0c + scol8, (char*)Bs + lo0);
        gload16(Wtg + (size_t)(n0 + 64 + wv * 16 + srow) * ldw + k0c + scol8, (char*)Bs + lo1);
    };

    stage(kbeg, 0);
    if (nk > 1) stage(kbeg + 32, 8192);
    if (nk > 2) stage(kbeg + 64, 16384);

    int bufb = 0;
    for (int kt = 0; kt < nk; ++kt) {
        // stage(kt) landed; up to 2 newer stages stay in flight across barrier
        if (kt < nk - 2)       asm volatile("s_waitcnt vmcnt(8)" ::: "memory");
        else if (kt == nk - 2) asm volatile("s_waitcnt vmcnt(4)" ::: "memory");
        else                   asm volatile("s_waitcnt vmcnt(0)" ::: "memory");
        __builtin_amdgcn_s_barrier();
        __builtin_amdgcn_sched_barrier(0);

        const u16* ard = As + (bufb >> 1) + (wr + lr) * 32 + fs;
        const u16* brd = Bs + (bufb >> 1) + (wc + lr) * 32 + fs;
        bf16x8 af[4], bfv[4];
        #pragma unroll
        for (int i = 0; i < 4; ++i) af[i]  = *(const bf16x8*)(ard + i * 512);
        #pragma unroll
        for (int j = 0; j < 4; ++j) bfv[j] = *(const bf16x8*)(brd + j * 512);

        __builtin_amdgcn_s_setprio(1);
        #pragma unroll
        for (int i = 0; i < 4; ++i)
            #pragma unroll
            for (int j = 0; j < 4; ++j)
                acc[i][j] = __builtin_amdgcn_mfma_f32_16x16x32_bf16(af[i], bfv[j], acc[i][j], 0, 0, 0);
        __builtin_amdgcn_s_setprio(0);

        __builtin_amdgcn_s_barrier();      // all waves' reads of buf(t%3) retired
        __builtin_amdgcn_sched_barrier(0);
        if (kt + 3 < nk) stage(kbeg + ((kt + 3) << 5), bufb);
        bufb = (bufb == 16384) ? 0 : bufb + 8192;
    }

    const int cr = hi << 2;
    #pragma unroll
    for (int i = 0; i < 4; ++i) {
        const int row = m0 + wr + i * 16 + cr;
        #pragma unroll
        for (int j = 0; j < 4; ++j) {
            const int cc = col0 + wc + j * 16 + lr;
            const float bv = addBias ? bias[cc] : 0.f;
            #pragma unroll
            for (int r = 0; r < 4; ++r)
                Cb[(size_t)(row + r) * ldc + cc] = f2bf(acc[i][j][r] + bv);
        }
    }
}

// Blocked GEMM (hw0/hw1/gate): z = g*nSplit + s.
__global__ __launch_bounds__(256) void gemm_blk(
    const u16* __restrict__ A1, int lda1, int a1_goff, int K1,
    const u16* __restrict__ A2, int lda2,
    const u16* __restrict__ Wt, int Ktot, const float* __restrict__ bias,
    u16* __restrict__ Cb, int ldc, int Nb,
    int nSplit, int Kchunk, long pstride)
{
    __shared__ u16 As[12288], Bs[12288];
    const int z = blockIdx.z;
    const int g = z / nSplit;
    const int s = z - g * nSplit;
    const int n0 = blockIdx.x << 7;
    const int m0 = blockIdx.y << 7;
    const u16* Wtg = Wt + (size_t)g * Nb * Ktot;
    gemm_core128(A1, lda1, a1_goff * g, K1, A2, lda2,
                 Wtg, Ktot, n0, bias, s == 0,
                 Cb + (size_t)s * pstride, ldc, g * Nb + n0,
                 m0, s * Kchunk, Kchunk >> 5, As, Bs);
}

// Table-driven branch GEMMs (w0 S=8, w1 S=2, w2 S=1), all N=1024.
struct BrEnt {
    const u16* A; const u16* Wt; const float* bias; u16* Cb;
    int lda, ldw, kbeg, nk, addBias;
};
struct BrTab { BrEnt e[11]; };

__global__ __launch_bounds__(256) void gemm_tab(BrTab tab) {
    __shared__ u16 As[12288], Bs[12288];
    const BrEnt e = tab.e[blockIdx.z];
    const int n0 = blockIdx.x << 7;
    const int m0 = blockIdx.y << 7;
    gemm_core128(e.A, e.lda, 0, 1 << 30, nullptr, 0,
                 e.Wt, e.ldw, n0, e.bias, e.addBias,
                 e.Cb, 1024, n0, m0, e.kbeg, e.nk, As, Bs);
}

// Sum S bf16 partials + RMSNorm(gain) + SiLU -> bf16. grid (rows, nseg).
struct Seg { const u16* in; long pstride; int S; const float* gain; int ld; };
struct NormArgs { Seg s[3]; };

__global__ __launch_bounds__(256) void norm_silu(NormArgs na, u16* __restrict__ out,
                                                 int ldout, int D)
{
    const int row = blockIdx.x, br = blockIdx.y;
    const Seg sg = na.s[br];
    const u16* ip = sg.in + (size_t)row * sg.ld;
    u16* op = out + (size_t)row * ldout + (size_t)br * D;
    const int t = threadIdx.x;
    const int nc = D >> 10;

    float4 cache[4];
    float ss = 0.f;
    #pragma unroll
    for (int c = 0; c < 4; ++c) if (c < nc) {
        int i = c * 1024 + t * 4;
        float4 v = {0.f, 0.f, 0.f, 0.f};
        for (int s2 = 0; s2 < sg.S; ++s2) {
            short4 h = *(const short4*)(ip + (size_t)s2 * sg.pstride + i);
            v.x += bf2f((u16)h.x); v.y += bf2f((u16)h.y);
            v.z += bf2f((u16)h.z); v.w += bf2f((u16)h.w);
        }
        cache[c] = v;
        ss += v.x * v.x + v.y * v.y + v.z * v.z + v.w * v.w;
    }
    #pragma unroll
    for (int o = 32; o > 0; o >>= 1) ss += __shfl_down(ss, o, 64);
    __shared__ float sred[4];
    if ((t & 63) == 0) sred[t >> 6] = ss;
    __syncthreads();
    float tot = sred[0] + sred[1] + sred[2] + sred[3];
    float scale = rsqrtf(tot / (float)D + 1e-4f);

    #pragma unroll
    for (int c = 0; c < 4; ++c) if (c < nc) {
        int i = c * 1024 + t * 4;
        float4 v = cache[c];
        float4 gv = *(const float4*)(sg.gain + i);
        float y; short4 h;
        y = v.x * scale * gv.x; h.x = (short)f2bf(y / (1.f + __expf(-y)));
        y = v.y * scale * gv.y; h.y = (short)f2bf(y / (1.f + __expf(-y)));
        y = v.z * scale * gv.z; h.z = (short)f2bf(y / (1.f + __expf(-y)));
        y = v.w * scale * gv.w; h.w = (short)f2bf(y / (1.f + __expf(-y)));
        *(short4*)(op + i) = h;
    }
}

// Merged: weight transpose+convert (bid<6944) and activation convert (rest).
__global__ __launch_bounds__(256) void prep_all(
    const float* __restrict__ w0, const float* __restrict__ w1, const float* __restrict__ w2,
    const float* __restrict__ hw0, const float* __restrict__ hw1, const float* __restrict__ gw,
    u16* __restrict__ w0t, u16* __restrict__ w1t, u16* __restrict__ w2t,
    u16* __restrict__ hw0t, u16* __restrict__ hw1t, u16* __restrict__ gwt,
    const float* __restrict__ deter, const float* __restrict__ stoch,
    const float* __restrict__ act,
    u16* __restrict__ dbf, u16* __restrict__ sbf, u16* __restrict__ abf)
{
    __shared__ float Ls[64][68];
    const int bid = blockIdx.x;
    const int t = threadIdx.x;
    if (bid < 6944) {
        const float* src; u16* dst; int K, N, loc;
        if (bid < 1024)      { src = w0;  dst = w0t;  K = 4096; N = 1024; loc = bid; }
        else if (bid < 1280) { src = w1;  dst = w1t;  K = 1024; N = 1024; loc = bid - 1024; }
        else if (bid < 1312) { src = w2;  dst = w2t;  K = 128;  N = 1024; loc = bid - 1280; }
        else if (bid < 4896) { src = hw0; dst = hw0t; K = 3584; N = 512;  loc = bid - 1312; }
        else if (bid < 5408) { src = hw1; dst = hw1t; K = 512;  N = 512;  loc = bid - 4896; }
        else                 { src = gw;  dst = gwt;  K = 512;  N = 1536; loc = bid - 5408; }
        const int ntiles = N >> 6, ktiles = K >> 6, tpg = ktiles * ntiles;
        const int g = loc / tpg, rem = loc % tpg;
        const int kt = rem / ntiles, nt = rem % ntiles;
        const float* sp = src + ((size_t)g * K + kt * 64) * N + nt * 64;
        u16* dp = dst + ((size_t)g * N + nt * 64) * K + kt * 64;

        const int rr = t >> 4, cc = (t & 15) << 2;
        #pragma unroll
        for (int p = 0; p < 4; ++p)
            *(float4*)&Ls[rr + 16 * p][cc] = *(const float4*)(sp + (size_t)(rr + 16 * p) * N + cc);
        __syncthreads();

        const int n = t >> 2, kk = (t & 3) << 4;
        u32 wo[8];
        #pragma unroll
        for (int j = 0; j < 8; ++j)
            wo[j] = pk2(Ls[kk + 2 * j][n], Ls[kk + 2 * j + 1][n]);
        u16* o = dp + (size_t)n * K + kk;
        int4 q0; q0.x = (int)wo[0]; q0.y = (int)wo[1]; q0.z = (int)wo[2]; q0.w = (int)wo[3];
        int4 q1; q1.x = (int)wo[4]; q1.y = (int)wo[5]; q1.z = (int)wo[6]; q1.w = (int)wo[7];
        *(int4*)o = q0;
        *(int4*)(o + 8) = q1;
    } else {
        const int i8 = ((bid - 6944) * 256 + t) * 8;
        const float* src; u16* dst; int off; bool nrm = false;
        if (i8 < 4194304)      { src = deter; dst = dbf; off = i8; }
        else if (i8 < 5242880) { src = stoch; dst = sbf; off = i8 - 4194304; }
        else                   { src = act;   dst = abf; off = i8 - 5242880; nrm = true; }
        float4 a = *(const float4*)(src + off);
        float4 b = *(const float4*)(src + off + 4);
        if (nrm) {
            a.x /= fmaxf(fabsf(a.x), 1.f); a.y /= fmaxf(fabsf(a.y), 1.f);
            a.z /= fmaxf(fabsf(a.z), 1.f); a.w /= fmaxf(fabsf(a.w), 1.f);
            b.x /= fmaxf(fabsf(b.x), 1.f); b.y /= fmaxf(fabsf(b.y), 1.f);
            b.z /= fmaxf(fabsf(b.z), 1.f); b.w /= fmaxf(fabsf(b.w), 1.f);
        }
        int4 o;
        o.x = (int)pk2(a.x, a.y); o.y = (int)pk2(a.z, a.w);
        o.z = (int)pk2(b.x, b.y); o.w = (int)pk2(b.z, b.w);
        *(int4*)(dst + off) = o;
    }
}

__device__ __forceinline__ float gru1(float r, float cc, float u, float d) {
    float reset = 1.f / (1.f + __expf(-r));
    float cand = tanhf(reset * cc);
    float upd = 1.f / (1.f + __expf(-(u - 1.f)));
    return upd * cand + (1.f - upd) * d;
}

__global__ __launch_bounds__(256) void gru_k(const u16* __restrict__ pre,
                                             const float* __restrict__ deter,
                                             float* __restrict__ out)
{
    int idx = (blockIdx.x * 256 + threadIdx.x) * 4;
    int b = idx >> 12;
    int c = idx & 4095;
    int g = c >> 9, ii = c & 511;
    const u16* p = pre + (size_t)b * 12288 + g * 1536 + ii;
    short4 pr = *(const short4*)p;
    short4 pc = *(const short4*)(p + 512);
    short4 pu = *(const short4*)(p + 1024);
    float4 dv = *(const float4*)(deter + idx);
    float4 o4;
    o4.x = gru1(bf2f((u16)pr.x), bf2f((u16)pc.x), bf2f((u16)pu.x), dv.x);
    o4.y = gru1(bf2f((u16)pr.y), bf2f((u16)pc.y), bf2f((u16)pu.y), dv.y);
    o4.z = gru1(bf2f((u16)pr.z), bf2f((u16)pc.z), bf2f((u16)pu.z), dv.z);
    o4.w = gru1(bf2f((u16)pr.w), bf2f((u16)pc.w), bf2f((u16)pu.w), dv.w);
    *(float4*)(out + idx) = o4;
}

extern "C" void kernel_launch(void* const* d_in, const int* in_sizes, int n_in,
                              void* d_out, int out_size, void* d_ws, size_t ws_size,
                              hipStream_t stream)
{
    (void)in_sizes; (void)n_in; (void)out_size; (void)ws_size;
    const float* stoch  = (const float*)d_in[0];
    const float* deter  = (const float*)d_in[1];
    const float* action = (const float*)d_in[2];
    const float* w0 = (const float*)d_in[3];
    const float* b0 = (const float*)d_in[4];
    const float* g0 = (const float*)d_in[5];
    const float* w1 = (const float*)d_in[6];
    const float* b1 = (const float*)d_in[7];
    const float* g1 = (const float*)d_in[8];
    const float* w2 = (const float*)d_in[9];
    const float* b2 = (const float*)d_in[10];
    const float* g2 = (const float*)d_in[11];
    const float* hw0 = (const float*)d_in[12];
    const float* hb0 = (const float*)d_in[13];
    const float* hg0 = (const float*)d_in[14];
    const float* hw1 = (const float*)d_in[15];
    const float* hb1 = (const float*)d_in[16];
    const float* hg1 = (const float*)d_in[17];
    const float* gw  = (const float*)d_in[18];
    const float* gb  = (const float*)d_in[19];
    float* out = (float*)d_out;

    // workspace (u16 units): scratch 16,777,216 | weights 28,442,624 | acts 12,713,984
    u16* scratch = (u16*)d_ws;
    u16* wreg = scratch + 16777216;
    u16* w0t  = wreg;
    u16* w1t  = w0t + 4194304;
    u16* w2t  = w1t + 1048576;
    u16* hw0t = w2t + 131072;
    u16* hw1t = hw0t + 14680064;
    u16* gwt  = hw1t + 2097152;
    u16* dbf  = wreg + 28442624;
    u16* sbf  = dbf + 4194304;
    u16* abf  = sbf + 1048576;
    u16* xbuf = abf + 131072;
    u16* hbuf = xbuf + 3145728;
    // scratch aliases (sequential lifetimes):
    u16* bp0 = scratch;               // 8 x [1024][1024]
    u16* bp1 = scratch + 8388608;     // 2 x [1024][1024]
    u16* bp2 = scratch + 10485760;    // 1 x [1024][1024]
    u16* hpart = scratch;             // up to 4 x [1024][4096]
    u16* gpre  = scratch;             // [1024][12288]

    dim3 blk(256);

    prep_all<<<9568, blk, 0, stream>>>(w0, w1, w2, hw0, hw1, gw,
                                       w0t, w1t, w2t, hw0t, hw1t, gwt,
                                       deter, stoch, action, dbf, sbf, abf);

    BrTab tab;
    for (int s = 0; s < 8; ++s)
        tab.e[s]   = { dbf, w0t, b0, bp0 + (size_t)s * 1048576, 4096, 4096, 512 * s, 16, s == 0 };
    for (int s = 0; s < 2; ++s)
        tab.e[8+s] = { sbf, w1t, b1, bp1 + (size_t)s * 1048576, 1024, 1024, 512 * s, 16, s == 0 };
    tab.e[10]      = { abf, w2t, b2, bp2,                       128,  128,  0,       4,  1 };
    gemm_tab<<<dim3(8, 8, 11), blk, 0, stream>>>(tab);

    NormArgs nb;
    nb.s[0] = { bp0, 1048576, 8, g0, 1024 };
    nb.s[1] = { bp1, 1048576, 2, g1, 1024 };
    nb.s[2] = { bp2, 0,       1, g2, 1024 };
    norm_silu<<<dim3(1024, 3), blk, 0, stream>>>(nb, xbuf, 3072, 1024);

    // hidden layer 0: A = [deter_g | x], K=3584, S=4 (Kchunk 896)
    gemm_blk<<<dim3(4, 8, 32), blk, 0, stream>>>(dbf, 4096, 512, 512, xbuf, 3072,
        hw0t, 3584, hb0, hpart, 4096, 512, 4, 896, 4194304);
    NormArgs nh0; nh0.s[0] = nh0.s[1] = nh0.s[2] = { hpart, 4194304, 4, hg0, 4096 };
    norm_silu<<<dim3(1024, 1), blk, 0, stream>>>(nh0, hbuf, 4096, 4096);

    // hidden layer 1: block-diagonal K=512, S=2 (Kchunk 256)
    gemm_blk<<<dim3(4, 8, 16), blk, 0, stream>>>(hbuf, 4096, 512, 512, nullptr, 0,
        hw1t, 512, hb1, hpart, 4096, 512, 2, 256, 4194304);
    NormArgs nh1; nh1.s[0] = nh1.s[1] = nh1.s[2] = { hpart, 4194304, 2, hg1, 4096 };
    norm_silu<<<dim3(1024, 1), blk, 0, stream>>>(nh1, hbuf, 4096, 4096);

    // gate: block-diagonal K=512 -> bf16 [1024][12288]
    gemm_blk<<<dim3(12, 8, 8), blk, 0, stream>>>(hbuf, 4096, 512, 512, nullptr, 0,
        gwt, 512, gb, gpre, 12288, 1536, 1, 512, 0);

    gru_k<<<4096, blk, 0, stream>>>(gpre, deter, out);
}